// Round 13
// baseline (3212.856 us; speedup 1.0000x reference)
//
#include <hip/hip_runtime.h>
#include <hip/hip_fp16.h>
#include <math.h>

#define DD 128
#define LEAKY 0.5f
#define RPB 128             // rows per bucket (power of 2)
#define RPB_SHIFT 7
#define MAXBIN 1024         // >= ceil(N/RPB); LDS arrays sized to this
#define CHUNK 2048          // edges per partition block
#define MAXBLK 1024         // >= ceil(E/CHUNK)
#define PACK_SHIFT 20       // col in low 20 bits, row_local (7b) above

// ---------------- device helper: gate 8 floats -> 8 halves ----------------

__device__ __forceinline__ void gate8(const float4* emb, const float4* zs,
                                      float4* gated_h, int i) {
    float4 e0 = emb[2 * i], e1 = emb[2 * i + 1];
    float4 z0 = zs[2 * i], z1 = zs[2 * i + 1];
    float g0 = e0.x * (2.f / (1.f + __expf(-z0.x)) - 1.f);
    float g1 = e0.y * (2.f / (1.f + __expf(-z0.y)) - 1.f);
    float g2 = e0.z * (2.f / (1.f + __expf(-z0.z)) - 1.f);
    float g3 = e0.w * (2.f / (1.f + __expf(-z0.w)) - 1.f);
    float g4 = e1.x * (2.f / (1.f + __expf(-z1.x)) - 1.f);
    float g5 = e1.y * (2.f / (1.f + __expf(-z1.y)) - 1.f);
    float g6 = e1.z * (2.f / (1.f + __expf(-z1.z)) - 1.f);
    float g7 = e1.w * (2.f / (1.f + __expf(-z1.w)) - 1.f);
    union { __half2 h[4]; float4 f; } u;
    u.h[0] = __floats2half2_rn(g0, g1);
    u.h[1] = __floats2half2_rn(g2, g3);
    u.h[2] = __floats2half2_rn(g4, g5);
    u.h[3] = __floats2half2_rn(g6, g7);
    gated_h[i] = u.f;
}

// ---------------- pass 1: gate (fp16) + per-block bucket histogram ----------

__global__ void gatehist_kernel(const float4* __restrict__ emb,
                                const float4* __restrict__ zs,
                                float4* __restrict__ gated_h, int n8,
                                const int* __restrict__ row, int* __restrict__ ghistT,
                                int E, int NBIN, int NBLK) {
    __shared__ int hist[MAXBIN];
    const int b = blockIdx.x;
    if (b < NBLK) {
        for (int i = threadIdx.x; i < NBIN; i += 256) hist[i] = 0;
        __syncthreads();
        const int base = b * CHUNK;
        #pragma unroll
        for (int it = 0; it < CHUNK / 256; ++it) {
            int e = base + it * 256 + threadIdx.x;
            if (e < E) atomicAdd(&hist[row[e] >> RPB_SHIFT], 1);
        }
        __syncthreads();
        for (int i = threadIdx.x; i < NBIN; i += 256)
            ghistT[(size_t)b * NBIN + i] = hist[i];
    }
    int i = blockIdx.x * blockDim.x + threadIdx.x;
    int stride = gridDim.x * blockDim.x;
    for (; i < n8; i += stride) gate8(emb, zs, gated_h, i);
}

// ---------------- pass 2: per-bin exclusive scan across blocks + zero done ---

__global__ void binscanT_kernel(const int* __restrict__ ghistT, int* __restrict__ gofsT,
                                int* __restrict__ btot, int* __restrict__ done,
                                int NBIN, int NBLK) {
    const int bin = blockIdx.x * 4 + (threadIdx.x >> 6);
    if (bin >= NBIN) return;
    const int lane = threadIdx.x & 63;
    int carry = 0;
    for (int k = 0; k < NBLK; k += 64) {
        int b = k + lane;
        int v = (b < NBLK) ? ghistT[(size_t)b * NBIN + bin] : 0;
        int x = v;
        #pragma unroll
        for (int off = 1; off < 64; off <<= 1) {
            int t = __shfl_up(x, off, 64);
            if (lane >= off) x += t;
        }
        if (b < NBLK) gofsT[(size_t)b * NBIN + bin] = carry + x - v;
        carry += __shfl(x, 63, 64);
    }
    if (lane == 0) { btot[bin] = carry; done[bin] = 0; }
}

// ---------------- pass 3: scatter + last-contributor row sort ----------------

__global__ void __launch_bounds__(256)
scatter_rowsort_kernel(const int* __restrict__ row, const int* __restrict__ col,
                       const float* __restrict__ val,
                       const int* __restrict__ gofsT, const int* __restrict__ ghistT,
                       const int* __restrict__ btot, int* __restrict__ done,
                       int2* __restrict__ sorted, int2* __restrict__ csr,
                       int* __restrict__ rowstart, int E, int N, int NBIN, int NBLK) {
    __shared__ int bsx[MAXBIN];       // exclusive scan of btot
    __shared__ int cur[MAXBIN];       // scatter cursors
    __shared__ int ws4[4];
    __shared__ int claims[MAXBIN];
    __shared__ int nclaim;
    __shared__ int cnt[RPB];
    __shared__ int rcur[RPB];
    const int b = blockIdx.x;
    const int tid = threadIdx.x;
    const int lane = tid & 63;
    const int wid = tid >> 6;

    if (tid == 0) nclaim = 0;
    for (int i = tid; i < NBIN; i += 256) bsx[i] = btot[i];
    __syncthreads();
    // exclusive scan of btot into bsx (4 elements/thread covers MAXBIN=1024)
    {
        int i0 = tid * 4;
        int c0 = (i0 + 0 < NBIN) ? bsx[i0 + 0] : 0;
        int c1 = (i0 + 1 < NBIN) ? bsx[i0 + 1] : 0;
        int c2 = (i0 + 2 < NBIN) ? bsx[i0 + 2] : 0;
        int c3 = (i0 + 3 < NBIN) ? bsx[i0 + 3] : 0;
        int s0 = c0, s1 = s0 + c1, s2 = s1 + c2, s3 = s2 + c3;
        int x = s3;
        #pragma unroll
        for (int off = 1; off < 64; off <<= 1) {
            int t = __shfl_up(x, off, 64);
            if (lane >= off) x += t;
        }
        if (lane == 63) ws4[wid] = x;
        __syncthreads();
        int base = 0;
        #pragma unroll
        for (int w = 0; w < 4; ++w) if (w < wid) base += ws4[w];
        int excl = base + x - s3;
        const size_t gbase = (size_t)b * NBIN;
        if (i0 + 0 < NBIN) { bsx[i0 + 0] = excl;      cur[i0 + 0] = excl      + gofsT[gbase + i0 + 0]; }
        if (i0 + 1 < NBIN) { bsx[i0 + 1] = excl + s0; cur[i0 + 1] = excl + s0 + gofsT[gbase + i0 + 1]; }
        if (i0 + 2 < NBIN) { bsx[i0 + 2] = excl + s1; cur[i0 + 2] = excl + s1 + gofsT[gbase + i0 + 2]; }
        if (i0 + 3 < NBIN) { bsx[i0 + 3] = excl + s2; cur[i0 + 3] = excl + s2 + gofsT[gbase + i0 + 3]; }
        __syncthreads();
    }
    // scatter this block's chunk into bucket order
    const int ebase = b * CHUNK;
    #pragma unroll
    for (int it = 0; it < CHUNK / 256; ++it) {
        int e = ebase + it * 256 + tid;
        if (e < E) {
            int r = row[e];
            int slot = atomicAdd(&cur[r >> RPB_SHIFT], 1);
            sorted[slot] = make_int2(col[e] | ((r & (RPB - 1)) << PACK_SHIFT),
                                     __float_as_int(val[e]));
        }
    }
    __syncthreads();
    // release our sorted[] writes, then signal per-bucket completion
    __threadfence();
    for (int i = tid; i < NBIN; i += 256) {
        int c = ghistT[(size_t)b * NBIN + i];
        int tot = btot[i];
        if (c > 0) {
            int old = atomicAdd(&done[i], c);
            if (old + c == tot) { int k = atomicAdd(&nclaim, 1); claims[k] = i; }
        } else if (b == 0 && tot == 0) {
            int k = atomicAdd(&nclaim, 1); claims[k] = i;   // empty bucket: still needs rowstart
        }
    }
    __syncthreads();
    __threadfence();   // acquire: other blocks' sorted[] writes now visible
    // row-sort each claimed bucket
    const int nq = nclaim;
    for (int q = 0; q < nq; ++q) {
        int bin = claims[q];
        int beg = bsx[bin];
        int end = (bin + 1 < NBIN) ? bsx[bin + 1] : E;
        for (int i = tid; i < RPB; i += 256) cnt[i] = 0;
        __syncthreads();
        for (int e = beg + tid; e < end; e += 256)
            atomicAdd(&cnt[((unsigned)sorted[e].x) >> PACK_SHIFT], 1);
        __syncthreads();
        int v = (tid < RPB) ? cnt[tid] : 0;
        int x = v;
        #pragma unroll
        for (int off = 1; off < 64; off <<= 1) {
            int t = __shfl_up(x, off, 64);
            if (lane >= off) x += t;
        }
        if (lane == 63) ws4[wid] = x;
        __syncthreads();
        int base = 0;
        #pragma unroll
        for (int w = 0; w < 4; ++w) if (w < wid) base += ws4[w];
        int excl = base + x - v;
        if (tid < RPB) {
            rcur[tid] = beg + excl;
            int r = bin * RPB + tid;
            if (r < N) rowstart[r] = beg + excl;
        }
        __syncthreads();
        for (int e = beg + tid; e < end; e += 256) {
            int2 cv = sorted[e];
            int rl = ((unsigned)cv.x) >> PACK_SHIFT;
            int slot = atomicAdd(&rcur[rl], 1);
            csr[slot] = make_int2(cv.x & ((1 << PACK_SHIFT) - 1), cv.y);
        }
        __syncthreads();
    }
    if (b == 0 && tid == 0) rowstart[N] = E;
}

// ---------------- pass 4: one wave per row, unroll-4 gather, nt csr/out ------

__global__ void gather_h_kernel(const int* __restrict__ starts,
                                const int2* __restrict__ csr,
                                const __half2* __restrict__ gated,
                                float* __restrict__ out, int N) {
    int gid = blockIdx.x * blockDim.x + threadIdx.x;
    int r = gid >> 6;
    if (r >= N) return;
    int lane = gid & 63;
    int beg = __builtin_amdgcn_readfirstlane(starts[r]);
    int end = __builtin_amdgcn_readfirstlane(starts[r + 1]);
    const long long* csr8 = (const long long*)csr;
    float2 acc = make_float2(0.f, 0.f);
    int j = beg;
    for (; j + 3 < end; j += 4) {
        long long w0 = __builtin_nontemporal_load(&csr8[j]);
        long long w1 = __builtin_nontemporal_load(&csr8[j + 1]);
        long long w2 = __builtin_nontemporal_load(&csr8[j + 2]);
        long long w3 = __builtin_nontemporal_load(&csr8[j + 3]);
        int cx0 = (int)w0, cx1 = (int)w1, cx2 = (int)w2, cx3 = (int)w3;
        float2 g0 = __half22float2(gated[(size_t)cx0 * 64 + lane]);
        float2 g1 = __half22float2(gated[(size_t)cx1 * 64 + lane]);
        float2 g2 = __half22float2(gated[(size_t)cx2 * 64 + lane]);
        float2 g3 = __half22float2(gated[(size_t)cx3 * 64 + lane]);
        float v0 = __int_as_float((int)(w0 >> 32));
        float v1 = __int_as_float((int)(w1 >> 32));
        float v2 = __int_as_float((int)(w2 >> 32));
        float v3 = __int_as_float((int)(w3 >> 32));
        acc.x += v0 * g0.x; acc.y += v0 * g0.y;
        acc.x += v1 * g1.x; acc.y += v1 * g1.y;
        acc.x += v2 * g2.x; acc.y += v2 * g2.y;
        acc.x += v3 * g3.x; acc.y += v3 * g3.y;
    }
    for (; j < end; ++j) {
        long long w = __builtin_nontemporal_load(&csr8[j]);
        int cx = (int)w;
        float2 g = __half22float2(gated[(size_t)cx * 64 + lane]);
        float v = __int_as_float((int)(w >> 32));
        acc.x += v * g.x; acc.y += v * g.y;
    }
    acc.x = acc.x > 0.f ? acc.x : LEAKY * acc.x;
    acc.y = acc.y > 0.f ? acc.y : LEAKY * acc.y;
    union { float2 f; double d; } u;
    u.f = acc;
    __builtin_nontemporal_store(u.d, (double*)&((float2*)out)[(size_t)r * 64 + lane]);
}

// ---------------- last-resort fallback (ws-free, round-1 proven) -------------

__global__ void zero4_kernel(float4* __restrict__ out, int n4) {
    int i = blockIdx.x * blockDim.x + threadIdx.x;
    int stride = gridDim.x * blockDim.x;
    float4 z = make_float4(0.f, 0.f, 0.f, 0.f);
    for (; i < n4; i += stride) out[i] = z;
}

__global__ void scatter_fused_kernel(const int* __restrict__ row,
                                     const int* __restrict__ col,
                                     const float* __restrict__ val,
                                     const float* __restrict__ emb,
                                     const float* __restrict__ zs,
                                     float* __restrict__ out, int E) {
    int gid = blockIdx.x * blockDim.x + threadIdx.x;
    int e = gid >> 5;
    if (e >= E) return;
    int lane = gid & 31;
    int r = row[e];
    int c = col[e];
    float v = val[e];
    const float4* ep = (const float4*)(emb + (size_t)c * DD);
    const float4* zp = (const float4*)(zs + (size_t)c * DD);
    float4 ev = ep[lane];
    float4 zv = zp[lane];
    float4 gv;
    gv.x = ev.x * (2.f / (1.f + __expf(-zv.x)) - 1.f);
    gv.y = ev.y * (2.f / (1.f + __expf(-zv.y)) - 1.f);
    gv.z = ev.z * (2.f / (1.f + __expf(-zv.z)) - 1.f);
    gv.w = ev.w * (2.f / (1.f + __expf(-zv.w)) - 1.f);
    float* o = out + (size_t)r * DD + lane * 4;
    atomicAdd(o + 0, v * gv.x);
    atomicAdd(o + 1, v * gv.y);
    atomicAdd(o + 2, v * gv.z);
    atomicAdd(o + 3, v * gv.w);
}

__global__ void leaky_kernel(float4* __restrict__ out, int n4) {
    int i = blockIdx.x * blockDim.x + threadIdx.x;
    int stride = gridDim.x * blockDim.x;
    for (; i < n4; i += stride) {
        float4 x = out[i];
        x.x = x.x > 0.f ? x.x : LEAKY * x.x;
        x.y = x.y > 0.f ? x.y : LEAKY * x.y;
        x.z = x.z > 0.f ? x.z : LEAKY * x.z;
        x.w = x.w > 0.f ? x.w : LEAKY * x.w;
        out[i] = x;
    }
}

// ---------------- launch ----------------

extern "C" void kernel_launch(void* const* d_in, const int* in_sizes, int n_in,
                              void* d_out, int out_size, void* d_ws, size_t ws_size,
                              hipStream_t stream) {
    const int* row_idx = (const int*)d_in[0];
    const int* col_idx = (const int*)d_in[1];
    const float* adj_vals = (const float*)d_in[2];
    const float* embeds = (const float*)d_in[3];
    const float* zishiying = (const float*)d_in[4];
    float* out = (float*)d_out;

    const int E = in_sizes[0];
    const int ND = in_sizes[3];        // N * 128
    const int N = ND / DD;
    const int n4 = ND / 4;
    const int n8 = ND / 8;
    const int NBIN = (N + RPB - 1) / RPB;
    const int NBLK = (E + CHUNK - 1) / CHUNK;

    // ws layout
    char* p = (char*)d_ws;
    __half2* gated = (__half2*)p;          p += (size_t)ND * 2;
    int* ghistT = (int*)p;                 p += (size_t)NBIN * NBLK * 4;
    int* gofsT = (int*)p;                  p += (size_t)NBIN * NBLK * 4;
    int* btot = (int*)p;                   p += (size_t)NBIN * 4;
    int* done = (int*)p;                   p += (size_t)NBIN * 4;
    int* rowstart = (int*)p;               p += (size_t)(N + 1) * 4;
    p = (char*)(((uintptr_t)p + 15) & ~(uintptr_t)15);
    int2* sorted = (int2*)p;               p += (size_t)E * 8;
    int2* csr = (int2*)p;                  p += (size_t)E * 8;
    const size_t need = (size_t)(p - (char*)d_ws);

    const int gb8 = min((n8 + 255) / 256, 2048);

    const bool ok = (NBIN <= MAXBIN) && (NBLK <= MAXBLK) && (N <= (1 << PACK_SHIFT)) &&
                    (ws_size >= need);

    if (ok) {
        int fused_grid = max(NBLK, gb8);
        hipLaunchKernelGGL(gatehist_kernel, dim3(fused_grid), dim3(256), 0, stream,
                           (const float4*)embeds, (const float4*)zishiying,
                           (float4*)gated, n8, row_idx, ghistT, E, NBIN, NBLK);
        hipLaunchKernelGGL(binscanT_kernel, dim3((NBIN + 3) / 4), dim3(256), 0, stream,
                           ghistT, gofsT, btot, done, NBIN, NBLK);
        hipLaunchKernelGGL(scatter_rowsort_kernel, dim3(NBLK), dim3(256), 0, stream,
                           row_idx, col_idx, adj_vals, gofsT, ghistT, btot, done,
                           sorted, csr, rowstart, E, N, NBIN, NBLK);
        long long total = (long long)N * 64;
        int blocks = (int)((total + 255) / 256);
        hipLaunchKernelGGL(gather_h_kernel, dim3(blocks), dim3(256), 0, stream,
                           rowstart, csr, gated, out, N);
        return;
    }

    // ---------- last-resort atomic path ----------
    const int gb = min((n4 + 255) / 256, 2048);
    hipLaunchKernelGGL(zero4_kernel, dim3(gb), dim3(256), 0, stream, (float4*)out, n4);
    {
        long long total = (long long)E * 32;
        int sblocks = (int)((total + 255) / 256);
        hipLaunchKernelGGL(scatter_fused_kernel, dim3(sblocks), dim3(256), 0, stream,
                           row_idx, col_idx, adj_vals, embeds, zishiying, out, E);
    }
    hipLaunchKernelGGL(leaky_kernel, dim3(gb), dim3(256), 0, stream, (float4*)out, n4);
}

// Round 14
// 135.111 us; speedup vs baseline: 23.7794x; 23.7794x over previous
//
#include <hip/hip_runtime.h>
#include <hip/hip_fp16.h>
#include <math.h>

#define DD 128
#define LEAKY 0.5f
#define RPB 128             // rows per bucket (power of 2)
#define RPB_SHIFT 7
#define MAXBIN 1024         // >= ceil(N/RPB); LDS hist/cursor = 4 KB
#define CHUNK 2048          // edges per partition block
#define MAXBLK 1024         // >= ceil(E/CHUNK)
#define PACK_SHIFT 20       // col in low 20 bits, row_local (7b) above

// ---------------- device helper: gate 8 floats -> 8 halves ----------------

__device__ __forceinline__ void gate8(const float4* emb, const float4* zs,
                                      float4* gated_h, int i) {
    float4 e0 = emb[2 * i], e1 = emb[2 * i + 1];
    float4 z0 = zs[2 * i], z1 = zs[2 * i + 1];
    float g0 = e0.x * (2.f / (1.f + __expf(-z0.x)) - 1.f);
    float g1 = e0.y * (2.f / (1.f + __expf(-z0.y)) - 1.f);
    float g2 = e0.z * (2.f / (1.f + __expf(-z0.z)) - 1.f);
    float g3 = e0.w * (2.f / (1.f + __expf(-z0.w)) - 1.f);
    float g4 = e1.x * (2.f / (1.f + __expf(-z1.x)) - 1.f);
    float g5 = e1.y * (2.f / (1.f + __expf(-z1.y)) - 1.f);
    float g6 = e1.z * (2.f / (1.f + __expf(-z1.z)) - 1.f);
    float g7 = e1.w * (2.f / (1.f + __expf(-z1.w)) - 1.f);
    union { __half2 h[4]; float4 f; } u;
    u.h[0] = __floats2half2_rn(g0, g1);
    u.h[1] = __floats2half2_rn(g2, g3);
    u.h[2] = __floats2half2_rn(g4, g5);
    u.h[3] = __floats2half2_rn(g6, g7);
    gated_h[i] = u.f;
}

// ---------------- fused pass: gate (fp16) + per-block bucket histogram -------

__global__ void gatehist_kernel(const float4* __restrict__ emb,
                                const float4* __restrict__ zs,
                                float4* __restrict__ gated_h, int n8,
                                const int* __restrict__ row, int* __restrict__ ghistT,
                                int E, int NBIN, int NBLK) {
    __shared__ int hist[MAXBIN];
    const int b = blockIdx.x;
    if (b < NBLK) {
        for (int i = threadIdx.x; i < NBIN; i += 256) hist[i] = 0;
        __syncthreads();
        const int base = b * CHUNK;
        #pragma unroll
        for (int it = 0; it < CHUNK / 256; ++it) {
            int e = base + it * 256 + threadIdx.x;
            if (e < E) atomicAdd(&hist[row[e] >> RPB_SHIFT], 1);
        }
        __syncthreads();
        for (int i = threadIdx.x; i < NBIN; i += 256)
            ghistT[(size_t)b * NBIN + i] = hist[i];
    }
    int i = blockIdx.x * blockDim.x + threadIdx.x;
    int stride = gridDim.x * blockDim.x;
    for (; i < n8; i += stride) gate8(emb, zs, gated_h, i);
}

// ---------------- pass B: per-bin exclusive scan across blocks (transposed) ---

__global__ void binscanT_kernel(const int* __restrict__ ghistT, int* __restrict__ gofsT,
                                int* __restrict__ btot, int NBIN, int NBLK) {
    const int bin = blockIdx.x * 4 + (threadIdx.x >> 6);
    if (bin >= NBIN) return;
    const int lane = threadIdx.x & 63;
    int carry = 0;
    for (int k = 0; k < NBLK; k += 64) {
        int b = k + lane;
        int v = (b < NBLK) ? ghistT[(size_t)b * NBIN + bin] : 0;
        int x = v;
        #pragma unroll
        for (int off = 1; off < 64; off <<= 1) {
            int t = __shfl_up(x, off, 64);
            if (lane >= off) x += t;
        }
        if (b < NBLK) gofsT[(size_t)b * NBIN + bin] = carry + x - v;
        carry += __shfl(x, 63, 64);
    }
    if (lane == 0) btot[bin] = carry;
}

// ---------------- pass C: counting-sort scatter; bstart computed in-block ----

__global__ void scatter_sortT_kernel(const int* __restrict__ row, const int* __restrict__ col,
                                     const float* __restrict__ val,
                                     const int* __restrict__ gofsT, const int* __restrict__ btot,
                                     int2* __restrict__ sorted, int E, int NBIN, int NBLK) {
    __shared__ int cur[MAXBIN];
    __shared__ int wsum[4];
    const int b = blockIdx.x;
    const int tid = threadIdx.x;
    const int lane = tid & 63;
    const int wid = tid >> 6;
    for (int i = tid; i < NBIN; i += 256) cur[i] = btot[i];
    __syncthreads();
    int i0 = tid * 4;
    int c0 = (i0 + 0 < NBIN) ? cur[i0 + 0] : 0;
    int c1 = (i0 + 1 < NBIN) ? cur[i0 + 1] : 0;
    int c2 = (i0 + 2 < NBIN) ? cur[i0 + 2] : 0;
    int c3 = (i0 + 3 < NBIN) ? cur[i0 + 3] : 0;
    int s0 = c0, s1 = s0 + c1, s2 = s1 + c2, s3 = s2 + c3;
    int x = s3;
    #pragma unroll
    for (int off = 1; off < 64; off <<= 1) {
        int t = __shfl_up(x, off, 64);
        if (lane >= off) x += t;
    }
    if (lane == 63) wsum[wid] = x;
    __syncthreads();
    int base = 0;
    #pragma unroll
    for (int w = 0; w < 4; ++w) if (w < wid) base += wsum[w];
    int excl = base + x - s3;
    const size_t gbase = (size_t)b * NBIN;
    if (i0 + 0 < NBIN) cur[i0 + 0] = excl + gofsT[gbase + i0 + 0];
    if (i0 + 1 < NBIN) cur[i0 + 1] = excl + s0 + gofsT[gbase + i0 + 1];
    if (i0 + 2 < NBIN) cur[i0 + 2] = excl + s1 + gofsT[gbase + i0 + 2];
    if (i0 + 3 < NBIN) cur[i0 + 3] = excl + s2 + gofsT[gbase + i0 + 3];
    __syncthreads();
    const int ebase = b * CHUNK;
    #pragma unroll
    for (int it = 0; it < CHUNK / 256; ++it) {
        int e = ebase + it * 256 + tid;
        if (e < E) {
            int r = row[e];
            int slot = atomicAdd(&cur[r >> RPB_SHIFT], 1);
            sorted[slot] = make_int2(col[e] | ((r & (RPB - 1)) << PACK_SHIFT),
                                     __float_as_int(val[e]));
        }
    }
}

// ---------------- pass D: within-bucket row sort; bstart computed in-block ---

__global__ void rowsortT_kernel(const int2* __restrict__ sorted,
                                const int* __restrict__ btot,
                                int2* __restrict__ csr,
                                int* __restrict__ rowstart, int N, int NBIN, int E) {
    __shared__ int bs[MAXBIN + 1];
    __shared__ int wsA[4];
    __shared__ int cnt[RPB];
    __shared__ int cur[RPB];
    __shared__ int wsB[4];
    const int bin = blockIdx.x;
    const int tid = threadIdx.x;
    const int lane = tid & 63;
    const int wid = tid >> 6;
    for (int i = tid; i < NBIN; i += 256) bs[i] = btot[i];
    __syncthreads();
    {
        int i0 = tid * 4;
        int c0 = (i0 + 0 < NBIN) ? bs[i0 + 0] : 0;
        int c1 = (i0 + 1 < NBIN) ? bs[i0 + 1] : 0;
        int c2 = (i0 + 2 < NBIN) ? bs[i0 + 2] : 0;
        int c3 = (i0 + 3 < NBIN) ? bs[i0 + 3] : 0;
        int s0 = c0, s1 = s0 + c1, s2 = s1 + c2, s3 = s2 + c3;
        int x = s3;
        #pragma unroll
        for (int off = 1; off < 64; off <<= 1) {
            int t = __shfl_up(x, off, 64);
            if (lane >= off) x += t;
        }
        if (lane == 63) wsA[wid] = x;
        __syncthreads();
        int base = 0;
        #pragma unroll
        for (int w = 0; w < 4; ++w) if (w < wid) base += wsA[w];
        int excl = base + x - s3;
        if (i0 + 0 < NBIN) bs[i0 + 0] = excl;
        if (i0 + 1 < NBIN) bs[i0 + 1] = excl + s0;
        if (i0 + 2 < NBIN) bs[i0 + 2] = excl + s1;
        if (i0 + 3 < NBIN) bs[i0 + 3] = excl + s2;
        if (tid == 0) bs[NBIN] = E;
    }
    for (int i = tid; i < RPB; i += 256) cnt[i] = 0;
    __syncthreads();
    const int beg = bs[bin], end = bs[bin + 1];
    for (int e = beg + tid; e < end; e += 256) {
        int rl = ((unsigned)sorted[e].x) >> PACK_SHIFT;
        atomicAdd(&cnt[rl], 1);
    }
    __syncthreads();
    int v = (tid < RPB) ? cnt[tid] : 0;
    int x = v;
    #pragma unroll
    for (int off = 1; off < 64; off <<= 1) {
        int t = __shfl_up(x, off, 64);
        if (lane >= off) x += t;
    }
    if (lane == 63) wsB[wid] = x;
    __syncthreads();
    int base = 0;
    #pragma unroll
    for (int w = 0; w < 4; ++w) if (w < wid) base += wsB[w];
    int excl = base + x - v;
    if (tid < RPB) {
        cur[tid] = beg + excl;
        int r = bin * RPB + tid;
        if (r < N) rowstart[r] = beg + excl;
    }
    if (tid == 0 && bin == 0) rowstart[N] = E;
    __syncthreads();
    for (int e = beg + tid; e < end; e += 256) {
        int2 cv = sorted[e];
        int rl = ((unsigned)cv.x) >> PACK_SHIFT;
        int slot = atomicAdd(&cur[rl], 1);
        csr[slot] = make_int2(cv.x & ((1 << PACK_SHIFT) - 1), cv.y);
    }
}

// ---------------- pass E: one wave per row, unroll-4 gather, nt csr/out ------
// csr loaded nontemporally (streamed once) and out stored nontemporally so the
// L2 stays filled with `gated` (the only reused array) during the gather.

__global__ void gather_h_kernel(const int* __restrict__ starts,
                                const int2* __restrict__ csr,
                                const __half2* __restrict__ gated,
                                float* __restrict__ out, int N) {
    int gid = blockIdx.x * blockDim.x + threadIdx.x;
    int r = gid >> 6;
    if (r >= N) return;
    int lane = gid & 63;
    int beg = __builtin_amdgcn_readfirstlane(starts[r]);
    int end = __builtin_amdgcn_readfirstlane(starts[r + 1]);
    const long long* csr8 = (const long long*)csr;
    float2 acc = make_float2(0.f, 0.f);
    int j = beg;
    for (; j + 3 < end; j += 4) {
        long long w0 = __builtin_nontemporal_load(&csr8[j]);
        long long w1 = __builtin_nontemporal_load(&csr8[j + 1]);
        long long w2 = __builtin_nontemporal_load(&csr8[j + 2]);
        long long w3 = __builtin_nontemporal_load(&csr8[j + 3]);
        int cx0 = (int)w0, cx1 = (int)w1, cx2 = (int)w2, cx3 = (int)w3;
        float2 g0 = __half22float2(gated[(size_t)cx0 * 64 + lane]);
        float2 g1 = __half22float2(gated[(size_t)cx1 * 64 + lane]);
        float2 g2 = __half22float2(gated[(size_t)cx2 * 64 + lane]);
        float2 g3 = __half22float2(gated[(size_t)cx3 * 64 + lane]);
        float v0 = __int_as_float((int)(w0 >> 32));
        float v1 = __int_as_float((int)(w1 >> 32));
        float v2 = __int_as_float((int)(w2 >> 32));
        float v3 = __int_as_float((int)(w3 >> 32));
        acc.x += v0 * g0.x; acc.y += v0 * g0.y;
        acc.x += v1 * g1.x; acc.y += v1 * g1.y;
        acc.x += v2 * g2.x; acc.y += v2 * g2.y;
        acc.x += v3 * g3.x; acc.y += v3 * g3.y;
    }
    for (; j < end; ++j) {
        long long w = __builtin_nontemporal_load(&csr8[j]);
        int cx = (int)w;
        float2 g = __half22float2(gated[(size_t)cx * 64 + lane]);
        float v = __int_as_float((int)(w >> 32));
        acc.x += v * g.x; acc.y += v * g.y;
    }
    acc.x = acc.x > 0.f ? acc.x : LEAKY * acc.x;
    acc.y = acc.y > 0.f ? acc.y : LEAKY * acc.y;
    union { float2 f; double d; } u;
    u.f = acc;
    __builtin_nontemporal_store(u.d, (double*)&((float2*)out)[(size_t)r * 64 + lane]);
}

// ---------------- last-resort fallback (ws-free) --------

__global__ void zero4_kernel(float4* __restrict__ out, int n4) {
    int i = blockIdx.x * blockDim.x + threadIdx.x;
    int stride = gridDim.x * blockDim.x;
    float4 z = make_float4(0.f, 0.f, 0.f, 0.f);
    for (; i < n4; i += stride) out[i] = z;
}

__global__ void scatter_fused_kernel(const int* __restrict__ row,
                                     const int* __restrict__ col,
                                     const float* __restrict__ val,
                                     const float* __restrict__ emb,
                                     const float* __restrict__ zs,
                                     float* __restrict__ out, int E) {
    int gid = blockIdx.x * blockDim.x + threadIdx.x;
    int e = gid >> 5;
    if (e >= E) return;
    int lane = gid & 31;
    int r = row[e];
    int c = col[e];
    float v = val[e];
    const float4* ep = (const float4*)(emb + (size_t)c * DD);
    const float4* zp = (const float4*)(zs + (size_t)c * DD);
    float4 ev = ep[lane];
    float4 zv = zp[lane];
    float4 gv;
    gv.x = ev.x * (2.f / (1.f + __expf(-zv.x)) - 1.f);
    gv.y = ev.y * (2.f / (1.f + __expf(-zv.y)) - 1.f);
    gv.z = ev.z * (2.f / (1.f + __expf(-zv.z)) - 1.f);
    gv.w = ev.w * (2.f / (1.f + __expf(-zv.w)) - 1.f);
    float* o = out + (size_t)r * DD + lane * 4;
    atomicAdd(o + 0, v * gv.x);
    atomicAdd(o + 1, v * gv.y);
    atomicAdd(o + 2, v * gv.z);
    atomicAdd(o + 3, v * gv.w);
}

__global__ void leaky_kernel(float4* __restrict__ out, int n4) {
    int i = blockIdx.x * blockDim.x + threadIdx.x;
    int stride = gridDim.x * blockDim.x;
    for (; i < n4; i += stride) {
        float4 x = out[i];
        x.x = x.x > 0.f ? x.x : LEAKY * x.x;
        x.y = x.y > 0.f ? x.y : LEAKY * x.y;
        x.z = x.z > 0.f ? x.z : LEAKY * x.z;
        x.w = x.w > 0.f ? x.w : LEAKY * x.w;
        out[i] = x;
    }
}

// ---------------- launch ----------------

extern "C" void kernel_launch(void* const* d_in, const int* in_sizes, int n_in,
                              void* d_out, int out_size, void* d_ws, size_t ws_size,
                              hipStream_t stream) {
    const int* row_idx = (const int*)d_in[0];
    const int* col_idx = (const int*)d_in[1];
    const float* adj_vals = (const float*)d_in[2];
    const float* embeds = (const float*)d_in[3];
    const float* zishiying = (const float*)d_in[4];
    float* out = (float*)d_out;

    const int E = in_sizes[0];
    const int ND = in_sizes[3];        // N * 128
    const int N = ND / DD;
    const int n4 = ND / 4;
    const int n8 = ND / 8;
    const int NBIN = (N + RPB - 1) / RPB;
    const int NBLK = (E + CHUNK - 1) / CHUNK;

    // ws layout
    char* p = (char*)d_ws;
    __half2* gated = (__half2*)p;          p += (size_t)ND * 2;
    int* ghistT = (int*)p;                 p += (size_t)NBIN * NBLK * 4;
    int* gofsT = (int*)p;                  p += (size_t)NBIN * NBLK * 4;
    int* btot = (int*)p;                   p += (size_t)NBIN * 4;
    int* rowstart = (int*)p;               p += (size_t)(N + 1) * 4;
    p = (char*)(((uintptr_t)p + 15) & ~(uintptr_t)15);
    int2* sorted = (int2*)p;               p += (size_t)E * 8;
    int2* csr = (int2*)p;                  p += (size_t)E * 8;
    const size_t need = (size_t)(p - (char*)d_ws);

    const int gb8 = min((n8 + 255) / 256, 2048);

    const bool ok = (NBIN <= MAXBIN) && (NBLK <= MAXBLK) && (N <= (1 << PACK_SHIFT)) &&
                    (ws_size >= need);

    if (ok) {
        int fused_grid = max(NBLK, gb8);
        hipLaunchKernelGGL(gatehist_kernel, dim3(fused_grid), dim3(256), 0, stream,
                           (const float4*)embeds, (const float4*)zishiying,
                           (float4*)gated, n8, row_idx, ghistT, E, NBIN, NBLK);
        hipLaunchKernelGGL(binscanT_kernel, dim3((NBIN + 3) / 4), dim3(256), 0, stream,
                           ghistT, gofsT, btot, NBIN, NBLK);
        hipLaunchKernelGGL(scatter_sortT_kernel, dim3(NBLK), dim3(256), 0, stream,
                           row_idx, col_idx, adj_vals, gofsT, btot, sorted, E, NBIN, NBLK);
        hipLaunchKernelGGL(rowsortT_kernel, dim3(NBIN), dim3(256), 0, stream,
                           sorted, btot, csr, rowstart, N, NBIN, E);
        long long total = (long long)N * 64;
        int blocks = (int)((total + 255) / 256);
        hipLaunchKernelGGL(gather_h_kernel, dim3(blocks), dim3(256), 0, stream,
                           rowstart, csr, gated, out, N);
        return;
    }

    // ---------- last-resort atomic path ----------
    const int gb = min((n4 + 255) / 256, 2048);
    hipLaunchKernelGGL(zero4_kernel, dim3(gb), dim3(256), 0, stream, (float4*)out, n4);
    {
        long long total = (long long)E * 32;
        int sblocks = (int)((total + 255) / 256);
        hipLaunchKernelGGL(scatter_fused_kernel, dim3(sblocks), dim3(256), 0, stream,
                           row_idx, col_idx, adj_vals, embeds, zishiying, out, E);
    }
    hipLaunchKernelGGL(leaky_kernel, dim3(gb), dim3(256), 0, stream, (float4*)out, n4);
}